// Round 7
// baseline (522.884 us; speedup 1.0000x reference)
//
#include <hip/hip_runtime.h>

// GraphPool v7 (identical to v5/v6; resubmit after broker timeouts).
// out[r] = max(feat[r], max_{k<deg(r)} feat[adj_deg[r][k]])
// Buckets of equal degree are contiguous; degree 0..10.
// D_FEAT = 128 floats = 32 vec4 per row. 32 lanes per row, 1 vec4/lane.

typedef float v4f __attribute__((ext_vector_type(4)));

#define ROW_F4 32          // vec4 elements per row (128 floats)
#define ROWS_PER_BLOCK 8   // 256 threads / 32 lanes-per-row

struct Params {
    const v4f* __restrict__ feat;
    v4f* __restrict__ out;
    const int* __restrict__ adj[10];  // adj_deg1..adj_deg10
    int begin[11];                    // begin[d] = first row of degree-d bucket
    int n_atoms;
};

__global__ __launch_bounds__(256) void graphpool_kernel(Params p) {
    const int row = blockIdx.x * ROWS_PER_BLOCK + (threadIdx.x >> 5);
    if (row >= p.n_atoms) return;
    const int lane = threadIdx.x & 31;

    // degree = number of bucket starts <= row (begin[1..10]); bucket 0 starts at 0
    int deg = 0;
#pragma unroll
    for (int d = 1; d <= 10; ++d) deg += (row >= p.begin[d]) ? 1 : 0;

    // self features: coalesced 512B per row
    v4f v = p.feat[(size_t)row * ROW_F4 + lane];

    if (deg > 0) {
        // select adjacency pointer with compile-time indices only (avoid scratch)
        const int* adjp = p.adj[0];
#pragma unroll
        for (int d = 2; d <= 10; ++d)
            if (deg == d) adjp = p.adj[d - 1];

        const int i = row - p.begin[deg];   // index within this degree bucket
        // one coalesced index load per row, broadcast via shuffle
        int a = (lane < deg) ? adjp[(size_t)i * deg + lane] : 0;

        // unroll-by-2: keep two gather loads in flight per 32-lane group
#pragma unroll 2
        for (int k = 0; k < deg; ++k) {
            const int idx = __shfl(a, k, 32);
            const v4f nv = p.feat[(size_t)idx * ROW_F4 + lane];
            v.x = fmaxf(v.x, nv.x);
            v.y = fmaxf(v.y, nv.y);
            v.z = fmaxf(v.z, nv.z);
            v.w = fmaxf(v.w, nv.w);
        }
    }

    // output is write-once, never re-read: nontemporal to preserve L3 for the gather table
    __builtin_nontemporal_store(v, &p.out[(size_t)row * ROW_F4 + lane]);
}

extern "C" void kernel_launch(void* const* d_in, const int* in_sizes, int n_in,
                              void* d_out, int out_size, void* d_ws, size_t ws_size,
                              hipStream_t stream) {
    // inputs: [0] atom_features (f32, N*128), [1] deg_slice (i32, 11*2),
    //         [2..11] adj_deg1..adj_deg10 (i32, n_d * d)
    Params p;
    p.feat = (const v4f*)d_in[0];
    p.out = (v4f*)d_out;

    const int n_atoms = in_sizes[0] / 128;
    p.n_atoms = n_atoms;

    int nd[11];
    int sum_d = 0;
    for (int d = 1; d <= 10; ++d) {
        nd[d] = in_sizes[1 + d] / d;
        sum_d += nd[d];
        p.adj[d - 1] = (const int*)d_in[1 + d];
    }
    nd[0] = n_atoms - sum_d;

    p.begin[0] = 0;
    for (int d = 1; d <= 10; ++d) p.begin[d] = p.begin[d - 1] + nd[d - 1];

    const int grid = (n_atoms + ROWS_PER_BLOCK - 1) / ROWS_PER_BLOCK;
    graphpool_kernel<<<grid, 256, 0, stream>>>(p);
}